// Round 10
// baseline (359.544 us; speedup 1.0000x reference)
//
#include <hip/hip_runtime.h>
#include <hip/hip_cooperative_groups.h>
#include <hip/hip_bf16.h>

namespace cg = cooperative_groups;

#define TT 512
#define BB 64
#define HH 512
#define KK 16

typedef __attribute__((ext_vector_type(8))) short bf16x8;
typedef __attribute__((ext_vector_type(4))) short bf16x4;
typedef __attribute__((ext_vector_type(4))) float f32x4;

// v_mfma_f32_16x16x16_bf16 — legacy gfx90a spelling, carried forward on gfx950.
// NOTE: do NOT gate on __has_builtin (false in the host pass); call directly.
#define MFMA_K16(A, B, C) __builtin_amdgcn_mfma_f32_16x16x16bf16_1k(A, B, C, 0, 0, 0)
#define MFMA_K32(A, B, C) __builtin_amdgcn_mfma_f32_16x16x32_bf16(A, B, C, 0, 0, 0)

__device__ __forceinline__ unsigned short f2bf(float f) {
    union { __hip_bfloat16 h; unsigned short u; } cvt;
    cvt.h = __float2bfloat16(f);
    return cvt.u;
}

// branch-free RNE f32->bf16 (inputs are finite non-NaN here)
__device__ __forceinline__ short rne_bf(float x) {
    unsigned u = __float_as_uint(x);
    u += 0x7fffu + ((u >> 16) & 1u);
    return (short)(u >> 16);
}

__device__ __forceinline__ float bf2f(short s) {
    return __uint_as_float(((unsigned)(unsigned short)s) << 16);
}

// ===========================================================================
// Shared phase bodies (used by BOTH the cooperative mega-kernel and the
// standalone fallback kernels — identical numerics on either path).
// ===========================================================================

// ---- phase 0: prep. blocks 0..63: W1 -> W1t bf16 [n][k]; block 64: W2t + out=0.
__device__ __forceinline__ void do_prep(int bi, int tx,
        const float* W1, const float* W2,
        unsigned short* W1t, unsigned short* W2t, float* out,
        float (*Ls)[65]) {
    if (bi < 64) {
        const int ti = bi & 7, tj = bi >> 3;
        const int r0 = ti * 64, c0 = tj * 64;
        const int r = tx >> 4, c4 = (tx & 15) * 4;
#pragma unroll
        for (int i = 0; i < 4; ++i) {
            float4 v = *(const float4*)(W1 + (size_t)(r0 + r + 16 * i) * HH + c0 + c4);
            Ls[c4 + 0][r + 16 * i] = v.x;
            Ls[c4 + 1][r + 16 * i] = v.y;
            Ls[c4 + 2][r + 16 * i] = v.z;
            Ls[c4 + 3][r + 16 * i] = v.w;
        }
        __syncthreads();
        const int rn = tx >> 4, k4 = (tx & 15) * 4;
#pragma unroll
        for (int i = 0; i < 4; ++i) {
            const int n = rn + 16 * i;
            ushort4 o;
            o.x = f2bf(Ls[n][k4 + 0]);
            o.y = f2bf(Ls[n][k4 + 1]);
            o.z = f2bf(Ls[n][k4 + 2]);
            o.w = f2bf(Ls[n][k4 + 3]);
            *(ushort4*)(W1t + (size_t)(c0 + n) * HH + r0 + k4) = o;
        }
    } else if (bi == 64) {
        if (tx == 0) out[0] = 0.0f;
        for (int idx = tx; idx < 16 * HH; idx += 256) {
            const int n = idx >> 9, k = idx & 511;
            W2t[idx] = f2bf(W2[k * KK + n]);
        }
    }
}

// ---- stage W2t into LDS (once per block, before em tiles)
__device__ __forceinline__ void do_stage_w2(int tx, const unsigned short* W2t,
                                            unsigned short* W2ts) {
    for (int i = tx; i < 16 * 64; i += 256) {
        const int n = i >> 6, kc = i & 63;
        *(bf16x8*)(W2ts + n * 520 + kc * 8) = *(const bf16x8*)(W2t + n * HH + kc * 8);
    }
}

// ---- phase 1: one 64-row em tile (R7's measured-43us body)
__device__ __forceinline__ void do_em_tile(int row0, int tx,
        const float* hidden, const unsigned short* W1t,
        const float* b1, const float* b2, float* em,
        const unsigned short* W2ts, unsigned char* stage) {
    unsigned short* As = (unsigned short*)stage;            // [64][40] bf16
    unsigned short* Bs = (unsigned short*)(stage + 5120);   // [512][32] bf16, k-swizzled
    unsigned short* Hb = (unsigned short*)stage;            // [64][264] bf16

    const int w = tx >> 6, lane = tx & 63;
    const int q = lane >> 4, nl = lane & 15;
    const int wm = w >> 1, wn = w & 1;

    f32x4 acc[2][16];
#pragma unroll
    for (int mt = 0; mt < 2; ++mt)
#pragma unroll
        for (int nt = 0; nt < 16; ++nt) acc[mt][nt] = (f32x4){0.f, 0.f, 0.f, 0.f};

    for (int kt = 0; kt < 16; ++kt) {
        const int k0 = kt * 32;
        __syncthreads();
        {
            const int r = tx >> 2, c8 = (tx & 3) * 8;
            const float* src = hidden + (size_t)(row0 + r) * HH + k0 + c8;
            float4 v0 = *(const float4*)(src);
            float4 v1 = *(const float4*)(src + 4);
            bf16x8 o;
            o[0] = (short)f2bf(v0.x); o[1] = (short)f2bf(v0.y);
            o[2] = (short)f2bf(v0.z); o[3] = (short)f2bf(v0.w);
            o[4] = (short)f2bf(v1.x); o[5] = (short)f2bf(v1.y);
            o[6] = (short)f2bf(v1.z); o[7] = (short)f2bf(v1.w);
            *(bf16x8*)(As + r * 40 + c8) = o;
        }
#pragma unroll
        for (int it = 0; it < 8; ++it) {
            const int c = it * 256 + tx;
            const int n = c >> 2, slot = c & 3;
            const int kc = slot ^ ((n >> 1) & 3);
            __builtin_amdgcn_global_load_lds(
                (const __attribute__((address_space(1))) void*)(W1t + (size_t)n * HH + k0 + kc * 8),
                (__attribute__((address_space(3))) void*)(Bs + c * 8),
                16, 0, 0);
        }
        __syncthreads();
        bf16x8 af[2];
#pragma unroll
        for (int mt = 0; mt < 2; ++mt)
            af[mt] = *(const bf16x8*)(As + (32 * wm + 16 * mt + nl) * 40 + q * 8);
#pragma unroll
        for (int nt = 0; nt < 16; ++nt) {
            const int n = 256 * wn + 16 * nt + nl;
            const int slot = q ^ ((n >> 1) & 3);
            bf16x8 bf = *(const bf16x8*)(Bs + n * 32 + slot * 8);
            acc[0][nt] = MFMA_K32(af[0], bf, acc[0][nt]);
            acc[1][nt] = MFMA_K32(af[1], bf, acc[1][nt]);
        }
    }

    f32x4 acc2 = (f32x4){0.f, 0.f, 0.f, 0.f};
    for (int c = 0; c < 2; ++c) {
        __syncthreads();
        if (wn == c) {
#pragma unroll
            for (int nt = 0; nt < 16; ++nt) {
                const float bv = b1[c * 256 + 16 * nt + nl];
#pragma unroll
                for (int mt = 0; mt < 2; ++mt) {
#pragma unroll
                    for (int r = 0; r < 4; ++r) {
                        float v = acc[mt][nt][r] + bv;
                        v = v > 0.f ? v : 0.f;
                        const int row = 32 * wm + 16 * mt + q * 4 + r;
                        Hb[row * 264 + nt * 16 + nl] = f2bf(v);
                    }
                }
            }
        }
        __syncthreads();
#pragma unroll
        for (int ks = 0; ks < 8; ++ks) {
            bf16x8 a2 = *(const bf16x8*)(Hb + (16 * w + nl) * 264 + ks * 32 + q * 8);
            bf16x8 b2f = *(const bf16x8*)(W2ts + nl * 520 + c * 256 + ks * 32 + q * 8);
            acc2 = MFMA_K32(a2, b2f, acc2);
        }
    }
#pragma unroll
    for (int r = 0; r < 4; ++r) {
        const int row = row0 + 16 * w + q * 4 + r;
        em[(size_t)row * KK + nl] = acc2[r] + b2[nl];
    }
}

// ---- phase 2: one chunk-slot (32 chunks x 64 batches; 16-step MFMA product)
__device__ __forceinline__ void do_chunk(int id, int lane,
        const float* em, const float* trans, const int* lens,
        unsigned short* Pfull, float* Cfull, float* Ppart, float* Cpart) {
    const int q = lane >> 4, col = lane & 15;
    const int c = id >> 6, b = id & 63;

    float mf[4];
    {
        float4 tv = *(const float4*)(trans + col * 16 + 4 * q);
        mf[0] = bf2f(rne_bf(__expf(tv.x)));
        mf[1] = bf2f(rne_bf(__expf(tv.y)));
        mf[2] = bf2f(rne_bf(__expf(tv.z)));
        mf[3] = bf2f(rne_bf(__expf(tv.w)));
    }
    const int Lm1 = lens[b] - 1;
    const int tb0 = 16 * c;

    float ebuf[8];
#pragma unroll
    for (int i = 0; i < 8; ++i)
        ebuf[i] = em[(size_t)((tb0 + i) * BB + b) * KK + col];

    bf16x4 gb;
#pragma unroll
    for (int i = 0; i < 4; ++i)
        gb[i] = (4 * q + i == col) ? rne_bf(1.0f) : (short)0;

    const f32x4 zc = (f32x4){0.f, 0.f, 0.f, 0.f};
    f32x4 d = (f32x4){0.f, 0.f, 0.f, 0.f};
    float K = 1.0f, rk = 1.0f, lk = 0.0f, Cacc = 0.0f;

    for (int sb = 0; sb < 16; sb += 8) {
        const bool refill = (sb == 0);
#pragma unroll
        for (int s8 = 0; s8 < 8; ++s8) {
            const int t = tb0 + sb + s8;
            const float eraw = ebuf[s8];
            if (refill)
                ebuf[s8] = em[(size_t)((t + 8) * BB + b) * KK + col];
            float ev = __expf(eraw);
            if ((s8 & 3) == 0 && (sb + s8) >= 4) {  // lagged renorm (off-chain)
                ev *= rk;
                Cacc += lk;
            }
            bf16x4 af;
            af[0] = rne_bf(ev * mf[0]); af[1] = rne_bf(ev * mf[1]);
            af[2] = rne_bf(ev * mf[2]); af[3] = rne_bf(ev * mf[3]);
            if (sb == 0 && s8 == 0 && c == 0) {  // t=0: A_0 = diag(exp(e_0))
#pragma unroll
                for (int i = 0; i < 4; ++i)
                    af[i] = (4 * q + i == col) ? rne_bf(ev) : (short)0;
            }
            d = MFMA_K16(af, gb, zc);
            if ((s8 & 3) == 1) {  // lagged capture of P[0][0]
                K = __shfl(d[0], 0, 64);
                const float Km = fmaxf(K, 1e-30f);
                rk = 1.0f / Km;
                lk = __logf(Km);
            }
            if (t == Lm1) {
#pragma unroll
                for (int r = 0; r < 4; ++r)
                    Ppart[b * 256 + (4 * q + r) * 16 + col] = d[r];
                if (lane == 0) Cpart[b] = Cacc;
            }
            gb[0] = rne_bf(d[0]); gb[1] = rne_bf(d[1]);
            gb[2] = rne_bf(d[2]); gb[3] = rne_bf(d[3]);
        }
    }
#pragma unroll
    for (int r = 0; r < 4; ++r)
        Pfull[(size_t)(b * 32 + c) * 256 + (4 * q + r) * 16 + col] = (unsigned short)rne_bf(d[r]);
    if (lane == 0) Cfull[b * 32 + c] = Cacc;
}

// ---- phase 3: gold + combine for one batch (needs 260 floats of LDS)
__device__ __forceinline__ void do_combine(int b, int tx,
        const float* em, const float* trans, const int* lens, const int* tags,
        const unsigned short* Pfull, const float* Cfull,
        const float* Ppart, const float* Cpart,
        float* out, float* lds260) {
    float* trs = lds260;
    float* red = lds260 + 256;
    trs[tx] = __logf(bf2f(rne_bf(__expf(trans[tx]))));
    __syncthreads();
    const int L = lens[b];
    float v = 0.0f;
#pragma unroll
    for (int p = 0; p < 2; ++p) {
        const int t = p * 256 + tx;
        if (t < L) {
            const int tg = tags[t * BB + b];
            float u = em[((size_t)t * BB + b) * KK + tg];
            if (t > 0) u += trs[tg * 16 + tags[(t - 1) * BB + b]];
            v += u;
        }
    }
#pragma unroll
    for (int dd = 1; dd < 64; dd <<= 1) v += __shfl_xor(v, dd, 64);
    if ((tx & 63) == 0) red[tx >> 6] = v;
    __syncthreads();

    if (tx < 64) {
        const int j = tx & 15;
        const int base = (tx >> 4) << 4;
        const int cstar = (L - 1) >> 4;
        float g = 1.0f, acc = 0.0f;
        for (int c = 0; c < 32; ++c) {
            if (c <= cstar) {
                float gn = 0.0f;
                if (c < cstar) {
                    const unsigned short* P = Pfull + (size_t)(b * 32 + c) * 256;
#pragma unroll
                    for (int k = 0; k < 16; ++k) {
                        const float gk = __shfl(g, base + k, 64);
                        gn += bf2f((short)P[j * 16 + k]) * gk;
                    }
                } else {
                    const float* P = Ppart + b * 256;
#pragma unroll
                    for (int k = 0; k < 16; ++k) {
                        const float gk = __shfl(g, base + k, 64);
                        gn += P[j * 16 + k] * gk;
                    }
                }
                float m = gn;
#pragma unroll
                for (int dd = 1; dd < 16; dd <<= 1) m = fmaxf(m, __shfl_xor(m, dd, 64));
                g = gn / m;
                acc += __logf(m) + ((c < cstar) ? Cfull[b * 32 + c] : Cpart[b]);
            }
        }
        float ssum = g;
#pragma unroll
        for (int dd = 1; dd < 16; dd <<= 1) ssum += __shfl_xor(ssum, dd, 64);
        const float fwd = acc + __logf(ssum);
        if (tx == 0)
            atomicAdd(out, fwd - (red[0] + red[1] + red[2] + red[3]));
    }
}

// ===========================================================================
// Cooperative mega-kernel — GRID-AGNOSTIC (any G >= 65): phases loop with
// stride G. Grid is sized by the launcher from the occupancy query.
// ===========================================================================
__global__ __launch_bounds__(256, 2)
void mega_kernel(const float* hidden, const float* W1, const float* b1,
                 const float* W2, const float* b2, const float* trans,
                 const int* lens, const int* tags, float* out,
                 float* em, unsigned short* W1t, unsigned short* W2t,
                 unsigned short* Pfull, float* Cfull, float* Ppart, float* Cpart) {
    cg::grid_group grid = cg::this_grid();
    __shared__ __align__(16) unsigned char smem[54528];
    unsigned short* W2ts = (unsigned short*)smem;   // 16640 B
    unsigned char* stage = smem + 16640;            // 37888 B

    const int tx = threadIdx.x, bi = blockIdx.x, G = gridDim.x;

    do_prep(bi, tx, W1, W2, W1t, W2t, out, (float (*)[65])stage);
    __threadfence();
    grid.sync();

    do_stage_w2(tx, W2t, W2ts);
    for (int rt = bi; rt < 512; rt += G)
        do_em_tile(rt * 64, tx, hidden, W1t, b1, b2, em, W2ts, stage);
    __threadfence();
    grid.sync();

    {
        const int w4 = tx >> 6;
        for (int id = bi * 4 + w4; id < 2048; id += G * 4)
            do_chunk(id, tx & 63, em, trans, lens, Pfull, Cfull, Ppart, Cpart);
    }
    __threadfence();
    grid.sync();

    if (bi < 64)
        do_combine(bi, tx, em, trans, lens, tags, Pfull, Cfull, Ppart, Cpart,
                   out, (float*)smem);
}

// ===========================================================================
// Standalone fallback kernels (same bodies; used if cooperative launch is
// unavailable or refused). Fallback == R7 structure (165 us, proven).
// ===========================================================================
__global__ __launch_bounds__(256)
void prep_kernel(const float* W1, const float* W2,
                 unsigned short* W1t, unsigned short* W2t, float* out) {
    __shared__ float Ls[64][65];
    do_prep(blockIdx.x, threadIdx.x, W1, W2, W1t, W2t, out, Ls);
}

__global__ __launch_bounds__(256, 2)
void em_kernel(const float* hidden, const unsigned short* W1t, const float* b1,
               const unsigned short* W2t, const float* b2, float* em) {
    __shared__ __align__(16) unsigned char smem[54528];
    unsigned short* W2ts = (unsigned short*)smem;
    unsigned char* stage = smem + 16640;
    do_stage_w2(threadIdx.x, W2t, W2ts);
    do_em_tile(blockIdx.x * 64, threadIdx.x, hidden, W1t, b1, b2, em, W2ts, stage);
}

__global__ __launch_bounds__(256)
void chunk_kernel(const float* em, const float* trans, const int* lens,
                  unsigned short* Pfull, float* Cfull, float* Ppart, float* Cpart) {
    do_chunk(blockIdx.x * 4 + (threadIdx.x >> 6), threadIdx.x & 63,
             em, trans, lens, Pfull, Cfull, Ppart, Cpart);
}

__global__ __launch_bounds__(256)
void combine_kernel(const float* em, const float* trans, const int* lens,
                    const int* tags, const unsigned short* Pfull, const float* Cfull,
                    const float* Ppart, const float* Cpart, float* out) {
    __shared__ float lds260[320];
    do_combine(blockIdx.x, threadIdx.x, em, trans, lens, tags,
               Pfull, Cfull, Ppart, Cpart, out, lds260);
}

extern "C" void kernel_launch(void* const* d_in, const int* in_sizes, int n_in,
                              void* d_out, int out_size, void* d_ws, size_t ws_size,
                              hipStream_t stream) {
    const float* hidden = (const float*)d_in[0];
    const float* W1     = (const float*)d_in[1];
    const float* b1     = (const float*)d_in[2];
    const float* W2     = (const float*)d_in[3];
    const float* b2     = (const float*)d_in[4];
    const float* trans  = (const float*)d_in[5];
    const int*   lens   = (const int*)d_in[6];
    const int*   tags   = (const int*)d_in[7];
    float* out = (float*)d_out;

    char* ws = (char*)d_ws;
    float* em = (float*)ws;                                   // [0, 2 MB)
    unsigned short* W1t = (unsigned short*)(ws + 2097152);    // 512 KB (dead after em)
    unsigned short* W2t = (unsigned short*)(ws + 2621440);    // 16 KB  (dead after em)
    unsigned short* Pfull = (unsigned short*)(ws + 2097152);  // 1 MB bf16, ALIASES W1t/W2t
    float* Cfull = (float*)(ws + 3145728);                    // 8 KB
    float* Ppart = (float*)(ws + 3153920);                    // 64 KB
    float* Cpart = (float*)(ws + 3219456);                    // 256 B

    // Host-side queries only (capture-safe): size the cooperative grid from
    // the actual occupancy instead of assuming 2 blocks/CU.
    int dev = 0;
    (void)hipGetDevice(&dev);
    int coop = 0, ncu = 0, occ = 0;
    (void)hipDeviceGetAttribute(&coop, hipDeviceAttributeCooperativeLaunch, dev);
    (void)hipDeviceGetAttribute(&ncu, hipDeviceAttributeMultiprocessorCount, dev);
    (void)hipOccupancyMaxActiveBlocksPerMultiprocessor(&occ, (const void*)mega_kernel, 256, 0);

    long Gl = (long)occ * (long)ncu;
    if (Gl > 512) Gl = 512;

    hipError_t e = hipErrorUnknown;
    if (coop && Gl >= 65) {
        void* args[] = {(void*)&hidden, (void*)&W1, (void*)&b1, (void*)&W2, (void*)&b2,
                        (void*)&trans, (void*)&lens, (void*)&tags, (void*)&out,
                        (void*)&em, (void*)&W1t, (void*)&W2t,
                        (void*)&Pfull, (void*)&Cfull, (void*)&Ppart, (void*)&Cpart};
        e = hipLaunchCooperativeKernel((const void*)mega_kernel, dim3((unsigned)Gl),
                                       dim3(256), args, 0, stream);
    }
    if (e != hipSuccess) {
        // deterministic fallback: same phase bodies, 4 launches (R7 parity)
        prep_kernel<<<65, 256, 0, stream>>>(W1, W2, W1t, W2t, out);
        em_kernel<<<512, 256, 0, stream>>>(hidden, W1t, b1, W2t, b2, em);
        chunk_kernel<<<512, 256, 0, stream>>>(em, trans, lens, Pfull, Cfull, Ppart, Cpart);
        combine_kernel<<<64, 256, 0, stream>>>(em, trans, lens, tags,
                                               Pfull, Cfull, Ppart, Cpart, out);
    }
}